// Round 5
// baseline (772.933 us; speedup 1.0000x reference)
//
#include <hip/hip_runtime.h>

typedef __bf16 bf16_t;
typedef __bf16 bf16x8 __attribute__((ext_vector_type(8)));
typedef float f32x4 __attribute__((ext_vector_type(4)));
typedef float f32x2 __attribute__((ext_vector_type(2)));

#define N_NODES 50000
#define N_PAD   50048   // padded to multiple of 128 for 128-row GEMM tiles
#define N_EDGES 400000
#define D_IN    256
#define D_HID   512
#define D_OUT   128
#define N_LAYERS 4
#define ZROW    N_PAD                  // index of the always-zero hw row (dummy gathers)
#define CSR_CAP (N_EDGES + 3 * N_NODES + 64)  // padded-slot capacity

#define AS1 __attribute__((address_space(1)))
#define AS3 __attribute__((address_space(3)))

// ---------------- init: zero deg/cursor, dummy-fill csr, zero ZROW rows, zero dinv pad ----

__global__ void init_misc(int* __restrict__ deg, int* __restrict__ cursor,
                          int* __restrict__ csr_src, float* __restrict__ dinv,
                          bf16_t* __restrict__ hwA, bf16_t* __restrict__ hwB) {
    int idx = blockIdx.x * blockDim.x + threadIdx.x;
    if (idx < CSR_CAP) csr_src[idx] = ZROW;
    if (idx < N_NODES) { deg[idx] = 0; cursor[idx] = 0; }
    if (idx < N_PAD - N_NODES) dinv[N_NODES + idx] = 0.0f;
    if (idx < D_HID / 2) {
        ((unsigned*)(hwA + (size_t)ZROW * D_HID))[idx] = 0u;
        ((unsigned*)(hwB + (size_t)ZROW * D_HID))[idx] = 0u;
    }
}

// ---------------- fp32 -> bf16 conversion (flat, for x) ----------------

__global__ void f32_to_bf16(const float* __restrict__ in, bf16_t* __restrict__ out, int n) {
    int idx = (blockIdx.x * blockDim.x + threadIdx.x) * 4;
    if (idx + 3 < n) {
        float4 v = *reinterpret_cast<const float4*>(in + idx);
        bf16_t o[4] = {(bf16_t)v.x, (bf16_t)v.y, (bf16_t)v.z, (bf16_t)v.w};
        *reinterpret_cast<uint2*>(out + idx) = *reinterpret_cast<const uint2*>(o);
    } else {
        for (int j = idx; j < n; j++) out[j] = (bf16_t)in[j];
    }
}

// ---------------- batched fp32 [R][C] -> bf16 transposed [C][R] for all weights --------
// z: 0 = W1 (256x512), 1..4 = Wc layer (512x512), 5 = W2 (512x128)

__global__ void transpose_all(const float* __restrict__ W1, const float* __restrict__ Wc,
                              const float* __restrict__ W2, bf16_t* __restrict__ W1t,
                              bf16_t* __restrict__ Wct, bf16_t* __restrict__ W2t) {
    const float* in; bf16_t* out; int R, C;
    const int z = blockIdx.z;
    if (z == 0)      { in = W1; out = W1t; R = D_IN;  C = D_HID; }
    else if (z <= 4) { in = Wc + (size_t)(z - 1) * D_HID * D_HID;
                       out = Wct + (size_t)(z - 1) * D_HID * D_HID; R = D_HID; C = D_HID; }
    else             { in = W2; out = W2t; R = D_HID; C = D_OUT; }

    const int c0 = blockIdx.x * 32;
    const int r0 = blockIdx.y * 32;
    if (c0 >= C || r0 >= R) return;
    __shared__ float tile[32][33];
    for (int i = threadIdx.y; i < 32; i += 8)
        tile[i][threadIdx.x] = in[(size_t)(r0 + i) * C + c0 + threadIdx.x];
    __syncthreads();
    for (int i = threadIdx.y; i < 32; i += 8)
        out[(size_t)(c0 + i) * R + r0 + threadIdx.x] = (bf16_t)tile[threadIdx.x][i];
}

// ---------------- degree / padded CSR build ----------------

__global__ void count_deg(const int* __restrict__ dst, int* __restrict__ deg, int E) {
    int e = blockIdx.x * blockDim.x + threadIdx.x;
    if (e < E) atomicAdd(&deg[dst[e]], 1);
}

__global__ void scan_reduce(const int* __restrict__ deg, int* __restrict__ partial, int N) {
    __shared__ int red[256];
    int base = blockIdx.x * 1024;
    int s = 0;
    for (int i = threadIdx.x; i < 1024; i += 256) {
        int idx = base + i;
        s += (idx < N) ? ((deg[idx] + 3) & ~3) : 0;   // padded slots
    }
    red[threadIdx.x] = s;
    __syncthreads();
    for (int off = 128; off > 0; off >>= 1) {
        if (threadIdx.x < off) red[threadIdx.x] += red[threadIdx.x + off];
        __syncthreads();
    }
    if (threadIdx.x == 0) partial[blockIdx.x] = red[0];
}

__global__ void scan_partials(int* __restrict__ partial, int nb,
                              int* __restrict__ row_start, int N) {
    if (threadIdx.x == 0 && blockIdx.x == 0) {
        int acc = 0;
        for (int i = 0; i < nb; i++) { int v = partial[i]; partial[i] = acc; acc += v; }
        row_start[N] = acc;   // total padded slots
    }
}

__global__ void scan_chunks(const int* __restrict__ deg, const int* __restrict__ partial,
                            int* __restrict__ row_start, float* __restrict__ dinv, int N) {
    __shared__ int buf[2][1024];
    int t = threadIdx.x;
    int gid = blockIdx.x * 1024 + t;
    int d = (gid < N) ? deg[gid] : 0;
    int v = (gid < N) ? ((d + 3) & ~3) : 0;           // padded slots
    int cur = 0;
    buf[0][t] = v;
    __syncthreads();
    for (int off = 1; off < 1024; off <<= 1) {
        int nxt = cur ^ 1;
        int val = buf[cur][t];
        if (t >= off) val += buf[cur][t - off];
        buf[nxt][t] = val;
        cur = nxt;
        __syncthreads();
    }
    int incl = buf[cur][t];
    if (gid < N) {
        row_start[gid] = partial[blockIdx.x] + incl - v;  // exclusive
        dinv[gid] = rsqrtf((float)(d + 1));               // +1 self loop
    }
}

__global__ void fill_csr(const int* __restrict__ ei, int E,
                         const int* __restrict__ row_start,
                         int* __restrict__ cursor, int* __restrict__ csr_src) {
    int e = blockIdx.x * blockDim.x + threadIdx.x;
    if (e < E) {
        int s = ei[e];
        int d = ei[E + e];
        int pos = atomicAdd(&cursor[d], 1);
        csr_src[row_start[d] + pos] = s;
    }
}

// ---------------- GEMM: C = act(rowscale * (A @ BT^T) + bias) ----------------
// R0-proven structure (best of 4 schedule experiments R1-R4): 128x128 tile,
// 4 waves, BK=64 single buffer, global_load_lds w=16, 4 blocks/CU.
// Used only for dnn1 and the first GCN GEMM (G0); later layers are fused.

template <bool F32OUT, bool RELU>
__global__ __launch_bounds__(256, 4) void gemm_tile(
    const bf16_t* __restrict__ A, const bf16_t* __restrict__ BT,
    const float* __restrict__ bias, const float* __restrict__ rowscale,
    void* __restrict__ Cv, int M, int N, int K)
{
    __shared__ __align__(16) char smem[32768];  // sA 16KB + sB 16KB; epilogue reuse
    bf16_t* sA = (bf16_t*)smem;
    bf16_t* sB = (bf16_t*)(smem + 128 * 128);
    bf16_t* sC = (bf16_t*)smem;                 // 64 x 136 bf16 = 17.4 KB

    int bxi, byi;
    if (gridDim.x == 4) {
        const int bid = blockIdx.y * 4 + blockIdx.x;     // dispatch-linear id
        const int T0 = (int)(gridDim.y * 4) & ~31;
        if (bid < T0) { int q = bid >> 5, r = bid & 31; byi = q * 8 + (r & 7); bxi = r >> 3; }
        else          { int t = bid - T0; byi = (T0 >> 2) + (t >> 2); bxi = t & 3; }
    } else { bxi = blockIdx.x; byi = blockIdx.y; }

    const int tid  = threadIdx.x;
    const int lane = tid & 63;
    const int wave = tid >> 6;
    const int bn = bxi * 128;
    const int bm = byi * 128;
    const int wm = (wave & 1) * 64;
    const int wn = (wave >> 1) * 64;
    const int lm = lane & 15;
    const int lq = lane >> 4;

    // staging: each 1KB wave-load covers 8 rows x 8 chunks; lane (r8,c8)
    const int r8 = lane >> 3;
    const int c8 = lane & 7;
    const int ksw = (c8 ^ r8) * 8;              // swizzled k-offset (elements)

    f32x4 acc[4][4] = {};

    const int nkb = K >> 6;
    for (int kb = 0; kb < nkb; kb++) {
        const int k0 = kb * 64;
#pragma unroll
        for (int r = 0; r < 4; r++) {               // A: 16 groups of 8 rows
            const int g = r * 4 + wave;
            __builtin_amdgcn_global_load_lds(
                (const AS1 unsigned int*)(A + (size_t)(bm + g * 8 + r8) * K + k0 + ksw),
                (AS3 unsigned int*)((AS3 char*)(AS3 bf16_t*)sA + g * 1024),
                16, 0, 0);
        }
#pragma unroll
        for (int r = 0; r < 4; r++) {               // B: 16 groups of 8 rows
            const int g = r * 4 + wave;
            __builtin_amdgcn_global_load_lds(
                (const AS1 unsigned int*)(BT + (size_t)(bn + g * 8 + r8) * K + k0 + ksw),
                (AS3 unsigned int*)((AS3 char*)(AS3 bf16_t*)sB + g * 1024),
                16, 0, 0);
        }
        __syncthreads();

#pragma unroll
        for (int s = 0; s < 2; s++) {               // two K=32 steps per BK=64
            bf16x8 af[4], bfr[4];
#pragma unroll
            for (int mt = 0; mt < 4; mt++) {
                const int R = wm + mt * 16 + lm;
                const int g = s * 4 + lq;
                af[mt] = *reinterpret_cast<bf16x8*>(&sA[R * 64 + ((g ^ (R & 7)) * 8)]);
            }
#pragma unroll
            for (int nt = 0; nt < 4; nt++) {
                const int R = wn + nt * 16 + lm;
                const int g = s * 4 + lq;
                bfr[nt] = *reinterpret_cast<bf16x8*>(&sB[R * 64 + ((g ^ (R & 7)) * 8)]);
            }
#pragma unroll
            for (int mt = 0; mt < 4; mt++)
#pragma unroll
                for (int nt = 0; nt < 4; nt++)
                    acc[mt][nt] = __builtin_amdgcn_mfma_f32_16x16x32_bf16(af[mt], bfr[nt], acc[mt][nt], 0, 0, 0);
        }
        __syncthreads();
    }

    if (!F32OUT) {
        // coalesced epilogue: 2 passes of 64 rows through LDS; sC row stride 136 elems
        const size_t rowbytes = (size_t)N * 2;
#pragma unroll
        for (int p = 0; p < 2; p++) {
            if (p) __syncthreads();
            if ((wave & 1) == p) {
#pragma unroll
                for (int nt = 0; nt < 4; nt++) {
                    const int col = wn + nt * 16 + lm;
                    const float bv = bias ? bias[bn + col] : 0.0f;
#pragma unroll
                    for (int mt = 0; mt < 4; mt++) {
#pragma unroll
                        for (int r = 0; r < 4; r++) {
                            const int lrow = mt * 16 + lq * 4 + r;
                            float v = acc[mt][nt][r] + bv;
                            if (rowscale) v *= rowscale[bm + p * 64 + lrow];
                            if (RELU) v = fmaxf(v, 0.0f);
                            sC[lrow * 136 + col] = (bf16_t)v;
                        }
                    }
                }
            }
            __syncthreads();
            char* outbase = (char*)Cv + (size_t)(bm + p * 64) * rowbytes + (size_t)bn * 2;
#pragma unroll
            for (int j = 0; j < 4; j++) {
                const int idx = j * 4096 + tid * 16;
                const int row = idx >> 8;            // 256 data bytes per row
                const int colb = idx & 255;
                *reinterpret_cast<uint4*>(outbase + (size_t)row * rowbytes + colb) =
                    *reinterpret_cast<const uint4*>((char*)sC + (size_t)row * 272 + colb);
            }
        }
    } else {
        // scattered epilogue (fp32 out): C/D layout col=lane&15, row=lq*4+reg
#pragma unroll
        for (int nt = 0; nt < 4; nt++) {
            const int col = bn + wn + nt * 16 + lm;
            const float bv = bias ? bias[col] : 0.0f;
#pragma unroll
            for (int mt = 0; mt < 4; mt++) {
#pragma unroll
                for (int r = 0; r < 4; r++) {
                    const int row = bm + wm + mt * 16 + lq * 4 + r;
                    if (row < M) {
                        float v = acc[mt][nt][r] + bv;
                        if (rowscale) v *= rowscale[row];
                        if (RELU) v = fmaxf(v, 0.0f);
                        ((float*)Cv)[(size_t)row * N + col] = v;
                    }
                }
            }
        }
    }
}

// ---------------- fused aggregate + next-layer GEMM ----------------
// Phase 1: block aggregates its 64 nodes (identical math to the old aggregate
//   kernel: h[n] = dinv[n]*(hw[n] + gather-sum) + bias_agg) and stores the
//   bf16 h rows into LDS, chunk-swizzled (chunk l of row r at l^(r&7)).
// Phase 2: 64x(NT*64) GEMM: A-frags from LDS (2-way bank, free), B-frags
//   loaded per-wave directly from L2 (Wct is 512KB, L2-resident; no staging,
//   no barriers). Output: bf16 hw' = dinv .* (h @ W) via coalesced LDS
//   epilogue, or fp32 out = h @ W2 + b2 scattered (F32OUT).
// Rationale: AGG is fabric-bound (MFMA 0%), GEMM is MFMA-bound (HBM ~1-2TB/s);
//   fusing lets co-resident blocks at different phases time-share both pipes,
//   and h never round-trips through global memory.
// 2 blocks/CU: 256 thr, VGPR<=256 (launch_bounds(256,2)), LDS 66048B.

template <int NT, bool F32OUT>
__global__ __launch_bounds__(256, 2) void fused_agg_gemm(
    const bf16_t* __restrict__ hw_src, const bf16_t* __restrict__ BT,
    const float* __restrict__ bias_agg, const float* __restrict__ bias_out,
    const float* __restrict__ dinv, const int* __restrict__ row_start,
    const int* __restrict__ csr_src, void* __restrict__ dst)
{
    __shared__ __align__(16) char smem[66048];  // hT 64KB / sC 64x516 bf16
    bf16_t* hT = (bf16_t*)smem;

    const int tid  = threadIdx.x;
    const int lane = tid & 63;
    const int w    = tid >> 6;
    const int m0   = blockIdx.x * 64;

    // ---------- phase 1: aggregate 16 nodes per wave into LDS ----------
    const char* hwb = (const char*)hw_src + lane * 16;
    for (int jn = 0; jn < 16; jn++) {
        const int row = w * 16 + jn;
        const int n   = m0 + row;
        uint4 ov = {0u, 0u, 0u, 0u};
        if (n < N_NODES) {
            const float dn = dinv[n];
            f32x2 acc[4];
            {   // self term (already scaled by dinv[n])
                uint4 u = *reinterpret_cast<const uint4*>(hwb + ((size_t)n << 10));
                const unsigned* wd = reinterpret_cast<const unsigned*>(&u);
#pragma unroll
                for (int j = 0; j < 4; j++) {
                    acc[j][0] = __uint_as_float(wd[j] << 16);
                    acc[j][1] = __uint_as_float(wd[j] & 0xffff0000u);
                }
            }
            const int beg = row_start[n];
            const int cnt = row_start[n + 1] - beg;      // multiple of 4
            const int* ip = csr_src + beg;
            int i = 0;
            for (; i + 8 <= cnt; i += 8) {
                const int4 a = *reinterpret_cast<const int4*>(ip + i);
                const int4 b = *reinterpret_cast<const int4*>(ip + i + 4);
                uint4 u[8];
                u[0] = *reinterpret_cast<const uint4*>(hwb + ((size_t)a.x << 10));
                u[1] = *reinterpret_cast<const uint4*>(hwb + ((size_t)a.y << 10));
                u[2] = *reinterpret_cast<const uint4*>(hwb + ((size_t)a.z << 10));
                u[3] = *reinterpret_cast<const uint4*>(hwb + ((size_t)a.w << 10));
                u[4] = *reinterpret_cast<const uint4*>(hwb + ((size_t)b.x << 10));
                u[5] = *reinterpret_cast<const uint4*>(hwb + ((size_t)b.y << 10));
                u[6] = *reinterpret_cast<const uint4*>(hwb + ((size_t)b.z << 10));
                u[7] = *reinterpret_cast<const uint4*>(hwb + ((size_t)b.w << 10));
#pragma unroll
                for (int q = 0; q < 8; q++) {
                    const unsigned* wd = reinterpret_cast<const unsigned*>(&u[q]);
#pragma unroll
                    for (int j = 0; j < 4; j++) {
                        f32x2 v;
                        v[0] = __uint_as_float(wd[j] << 16);
                        v[1] = __uint_as_float(wd[j] & 0xffff0000u);
                        acc[j] += v;
                    }
                }
            }
            if (i < cnt) {                               // one final 4-slot chunk
                const int4 a = *reinterpret_cast<const int4*>(ip + i);
                uint4 u[4];
                u[0] = *reinterpret_cast<const uint4*>(hwb + ((size_t)a.x << 10));
                u[1] = *reinterpret_cast<const uint4*>(hwb + ((size_t)a.y << 10));
                u[2] = *reinterpret_cast<const uint4*>(hwb + ((size_t)a.z << 10));
                u[3] = *reinterpret_cast<const uint4*>(hwb + ((size_t)a.w << 10));
#pragma unroll
                for (int q = 0; q < 4; q++) {
                    const unsigned* wd = reinterpret_cast<const unsigned*>(&u[q]);
#pragma unroll
                    for (int j = 0; j < 4; j++) {
                        f32x2 v;
                        v[0] = __uint_as_float(wd[j] << 16);
                        v[1] = __uint_as_float(wd[j] & 0xffff0000u);
                        acc[j] += v;
                    }
                }
            }
            const int f = lane * 8;
            bf16_t outv[8];
#pragma unroll
            for (int j = 0; j < 4; j++) {
                outv[2 * j]     = (bf16_t)(fmaf(dn, acc[j][0], bias_agg[f + 2 * j]));
                outv[2 * j + 1] = (bf16_t)(fmaf(dn, acc[j][1], bias_agg[f + 2 * j + 1]));
            }
            ov = *reinterpret_cast<const uint4*>(outv);
        }
        // swizzled LDS store: chunk `lane` of row `row` at position lane^(row&7)
        *reinterpret_cast<uint4*>(hT + (size_t)row * 512 + ((lane ^ (row & 7)) * 8)) = ov;
    }
    __syncthreads();

    // ---------- phase 2: GEMM 64 x (NT*64), K=512, B direct from L2 ----------
    const int lm = lane & 15;
    const int lq = lane >> 4;
    const int wn = w * (NT * 16);

    f32x4 acc[4][NT] = {};
#pragma unroll 2
    for (int s = 0; s < 16; s++) {
        bf16x8 af[4], bfr[NT];
#pragma unroll
        for (int mt = 0; mt < 4; mt++) {
            const int R = mt * 16 + lm;
            const int g = s * 4 + lq;
            af[mt] = *reinterpret_cast<bf16x8*>(&hT[(size_t)R * 512 + ((g ^ (R & 7)) * 8)]);
        }
#pragma unroll
        for (int nt = 0; nt < NT; nt++)
            bfr[nt] = *reinterpret_cast<const bf16x8*>(
                BT + (size_t)(wn + nt * 16 + lm) * 512 + s * 32 + lq * 8);
#pragma unroll
        for (int mt = 0; mt < 4; mt++)
#pragma unroll
            for (int nt = 0; nt < NT; nt++)
                acc[mt][nt] = __builtin_amdgcn_mfma_f32_16x16x32_bf16(af[mt], bfr[nt], acc[mt][nt], 0, 0, 0);
    }

    if (!F32OUT) {
        // hw' = dinv .* (h @ W); coalesced via LDS (stride 516 elems = 1032B)
        __syncthreads();                       // all hT reads done; reuse smem
        bf16_t* sC = (bf16_t*)smem;
#pragma unroll
        for (int nt = 0; nt < NT; nt++) {
            const int col = wn + nt * 16 + lm;
#pragma unroll
            for (int mt = 0; mt < 4; mt++) {
#pragma unroll
                for (int r = 0; r < 4; r++) {
                    const int lrow = mt * 16 + lq * 4 + r;
                    sC[(size_t)lrow * 516 + col] = (bf16_t)(acc[mt][nt][r] * dinv[m0 + lrow]);
                }
            }
        }
        __syncthreads();
        char* outb = (char*)dst + (size_t)m0 * 1024;
#pragma unroll
        for (int jj = 0; jj < 16; jj++) {
            const int idx  = jj * 4096 + tid * 16;
            const int row  = idx >> 10;            // 1024 data bytes per row
            const int colb = idx & 1023;
            *reinterpret_cast<uint4*>(outb + (size_t)row * 1024 + colb) =
                *reinterpret_cast<const uint4*>((char*)smem + (size_t)row * 1032 + colb);
        }
    } else {
        // dnn2: out = h @ W2 + b2, fp32 scattered, row guard
#pragma unroll
        for (int nt = 0; nt < NT; nt++) {
            const int col = wn + nt * 16 + lm;
            const float bv = bias_out[col];
#pragma unroll
            for (int mt = 0; mt < 4; mt++) {
#pragma unroll
                for (int r = 0; r < 4; r++) {
                    const int row = m0 + mt * 16 + lq * 4 + r;
                    if (row < N_NODES)
                        ((float*)dst)[(size_t)row * D_OUT + col] = acc[mt][nt][r] + bv;
                }
            }
        }
    }
}

// ---------------- orchestration ----------------

extern "C" void kernel_launch(void* const* d_in, const int* in_sizes, int n_in,
                              void* d_out, int out_size, void* d_ws, size_t ws_size,
                              hipStream_t stream) {
    const int N = N_NODES, E = N_EDGES;

    const float* x  = (const float*)d_in[0];
    const int*   ei = (const int*)d_in[1];
    const float* W1 = (const float*)d_in[2];
    const float* b1 = (const float*)d_in[3];
    const float* Wc = (const float*)d_in[4];
    const float* bc = (const float*)d_in[5];
    const float* W2 = (const float*)d_in[6];
    const float* b2 = (const float*)d_in[7];
    float* out = (float*)d_out;

    char* ws = (char*)d_ws;
    size_t off = 0;
    auto alloc = [&](size_t bytes) -> void* {
        void* p = ws + off;
        off += (bytes + 255) & ~(size_t)255;
        return p;
    };
    int*    deg       = (int*)alloc((size_t)N * 4);
    int*    cursor    = (int*)alloc((size_t)N * 4);
    int*    row_start = (int*)alloc((size_t)(N + 1) * 4);
    int*    partial   = (int*)alloc(256 * 4);
    float*  dinv      = (float*)alloc((size_t)N_PAD * 4);
    int*    csr_src   = (int*)alloc((size_t)CSR_CAP * 4);
    bf16_t* hwA       = (bf16_t*)alloc((size_t)(N_PAD + 1) * D_HID * 2);  // +1: ZROW
    bf16_t* hwB       = (bf16_t*)alloc((size_t)(N_PAD + 1) * D_HID * 2);  // +1: ZROW
    bf16_t* xb        = (bf16_t*)alloc((size_t)N_PAD * D_IN * 2);
    bf16_t* W1t       = (bf16_t*)alloc((size_t)D_HID * D_IN * 2);
    bf16_t* Wct       = (bf16_t*)alloc((size_t)N_LAYERS * D_HID * D_HID * 2);
    bf16_t* W2t       = (bf16_t*)alloc((size_t)D_OUT * D_HID * 2);

    // init (zero deg/cursor, dummy csr fill, zero ZROW rows, zero dinv pad)
    init_misc<<<(CSR_CAP + 255) / 256, 256, 0, stream>>>(deg, cursor, csr_src, dinv, hwA, hwB);

    // conversions
    {
        int n = N * D_IN;
        f32_to_bf16<<<(n / 4 + 255) / 256, 256, 0, stream>>>(x, xb, n);
        transpose_all<<<dim3(16, 16, 6), dim3(32, 8), 0, stream>>>(W1, Wc, W2, W1t, Wct, W2t);
    }

    // padded CSR build
    count_deg<<<(E + 255) / 256, 256, 0, stream>>>(ei + E, deg, E);
    const int nch = (N + 1023) / 1024;
    scan_reduce<<<nch, 256, 0, stream>>>(deg, partial, N);
    scan_partials<<<1, 64, 0, stream>>>(partial, nch, row_start, N);
    scan_chunks<<<nch, 1024, 0, stream>>>(deg, partial, row_start, dinv, N);
    fill_csr<<<(E + 255) / 256, 256, 0, stream>>>(ei, E, row_start, cursor, csr_src);

    const dim3 blk(256);
    const int mg = N_PAD / 128;   // 391
    const int fg = N_PAD / 64;    // 782 fused blocks

    // dnn1: h = relu(x @ W1 + b1)  -> hwB
    gemm_tile<false, true><<<dim3(D_HID / 128, mg), blk, 0, stream>>>(
        xb, W1t, b1, nullptr, hwB, N_PAD, D_HID, D_IN);

    // G0: hw0 = dinv .* (h @ Wc[0]) -> hwA
    gemm_tile<false, false><<<dim3(D_HID / 128, mg), blk, 0, stream>>>(
        hwB, Wct, nullptr, dinv, hwA, N_PAD, D_HID, D_HID);

    // F1: h1 = agg(hwA, bc0); hw1 = dinv .* (h1 @ Wc[1]) -> hwB
    fused_agg_gemm<8, false><<<fg, blk, 0, stream>>>(
        hwA, Wct + (size_t)1 * D_HID * D_HID, bc, nullptr,
        dinv, row_start, csr_src, hwB);

    // F2: h2 = agg(hwB, bc1); hw2 = dinv .* (h2 @ Wc[2]) -> hwA
    fused_agg_gemm<8, false><<<fg, blk, 0, stream>>>(
        hwB, Wct + (size_t)2 * D_HID * D_HID, bc + D_HID, nullptr,
        dinv, row_start, csr_src, hwA);

    // F3: h3 = agg(hwA, bc2); hw3 = dinv .* (h3 @ Wc[3]) -> hwB
    fused_agg_gemm<8, false><<<fg, blk, 0, stream>>>(
        hwA, Wct + (size_t)3 * D_HID * D_HID, bc + 2 * D_HID, nullptr,
        dinv, row_start, csr_src, hwB);

    // F4: h4 = agg(hwB, bc3); out = h4 @ W2 + b2 (fp32)
    fused_agg_gemm<2, true><<<fg, blk, 0, stream>>>(
        hwB, W2t, bc + 3 * D_HID, b2,
        dinv, row_start, csr_src, out);
}

// Round 7
// 529.780 us; speedup vs baseline: 1.4590x; 1.4590x over previous
//
#include <hip/hip_runtime.h>

typedef __bf16 bf16_t;
typedef __bf16 bf16x8 __attribute__((ext_vector_type(8)));
typedef float f32x4 __attribute__((ext_vector_type(4)));
typedef float f32x2 __attribute__((ext_vector_type(2)));

#define N_NODES 50000
#define N_PAD   50048   // padded to multiple of 128 for 128-row GEMM tiles
#define N_EDGES 400000
#define D_IN    256
#define D_HID   512
#define D_OUT   128
#define N_LAYERS 4
#define ZROW    N_PAD                  // index of the always-zero table row (dummy gathers)
#define CSR_CAP (N_EDGES + 3 * N_NODES + 64)  // padded-slot capacity
#define PZ_FLOATS (3 * 512 * 512)      // P12,Q,P zero region

#define AS1 __attribute__((address_space(1)))
#define AS3 __attribute__((address_space(3)))

// ---------------- init: zero deg/cursor, dummy-fill csr, zero pads/ZROW, zero P bufs ----

__global__ void init_misc(int* __restrict__ deg, int* __restrict__ cursor,
                          int* __restrict__ csr_src, float* __restrict__ dinv,
                          float* __restrict__ u0, float* __restrict__ u1,
                          float* __restrict__ u2, bf16_t* __restrict__ FA,
                          bf16_t* __restrict__ FB, float* __restrict__ Pz) {
    int idx = blockIdx.x * blockDim.x + threadIdx.x;
    if (idx < CSR_CAP) csr_src[idx] = ZROW;
    if (idx < N_NODES) { deg[idx] = 0; cursor[idx] = 0; }
    if (idx < N_PAD - N_NODES) dinv[N_NODES + idx] = 0.0f;
    if (idx < N_PAD + 1 - N_NODES) {
        u0[N_NODES + idx] = 0.0f; u1[N_NODES + idx] = 0.0f; u2[N_NODES + idx] = 0.0f;
    }
    if (idx < 64) {   // ZROW of the 128-wide gather tables (128 bf16 = 64 dwords)
        ((unsigned*)(FA + (size_t)ZROW * D_OUT))[idx] = 0u;
        ((unsigned*)(FB + (size_t)ZROW * D_OUT))[idx] = 0u;
    }
    if (idx < PZ_FLOATS) Pz[idx] = 0.0f;
}

// ---------------- fp32 -> bf16 conversion (flat, for x) ----------------

__global__ void f32_to_bf16(const float* __restrict__ in, bf16_t* __restrict__ out, int n) {
    int idx = (blockIdx.x * blockDim.x + threadIdx.x) * 4;
    if (idx + 3 < n) {
        float4 v = *reinterpret_cast<const float4*>(in + idx);
        bf16_t o[4] = {(bf16_t)v.x, (bf16_t)v.y, (bf16_t)v.z, (bf16_t)v.w};
        *reinterpret_cast<uint2*>(out + idx) = *reinterpret_cast<const uint2*>(o);
    } else {
        for (int j = idx; j < n; j++) out[j] = (bf16_t)in[j];
    }
}

// ---------------- transposes: W1 -> bf16 W1t; C2,C4,W2 -> fp32 transposed ----------------
// z: 0 = W1 (256x512 -> bf16), 1 = Wc[1] (C2, fp32T), 2 = Wc[3] (C4, fp32T), 3 = W2 (fp32T)

__global__ void transpose_all(const float* __restrict__ W1, const float* __restrict__ Wc,
                              const float* __restrict__ W2, bf16_t* __restrict__ W1t,
                              float* __restrict__ W2cT, float* __restrict__ W4cT,
                              float* __restrict__ W2T) {
    const float* in; int R, C; bf16_t* outb = nullptr; float* outf = nullptr;
    const int z = blockIdx.z;
    if (z == 0)      { in = W1; R = D_IN;  C = D_HID; outb = W1t; }
    else if (z == 1) { in = Wc + (size_t)1 * D_HID * D_HID; R = D_HID; C = D_HID; outf = W2cT; }
    else if (z == 2) { in = Wc + (size_t)3 * D_HID * D_HID; R = D_HID; C = D_HID; outf = W4cT; }
    else             { in = W2; R = D_HID; C = D_OUT; outf = W2T; }

    const int c0 = blockIdx.x * 32;
    const int r0 = blockIdx.y * 32;
    if (c0 >= C || r0 >= R) return;
    __shared__ float tile[32][33];
    for (int i = threadIdx.y; i < 32; i += 8)
        tile[i][threadIdx.x] = in[(size_t)(r0 + i) * C + c0 + threadIdx.x];
    __syncthreads();
    for (int i = threadIdx.y; i < 32; i += 8) {
        if (outb) outb[(size_t)(c0 + i) * R + r0 + threadIdx.x] = (bf16_t)tile[threadIdx.x][i];
        else      outf[(size_t)(c0 + i) * R + r0 + threadIdx.x] = tile[threadIdx.x][i];
    }
}

// ---------------- degree / padded CSR build ----------------

__global__ void count_deg(const int* __restrict__ dst, int* __restrict__ deg, int E) {
    int e = blockIdx.x * blockDim.x + threadIdx.x;
    if (e < E) atomicAdd(&deg[dst[e]], 1);
}

__global__ void scan_reduce(const int* __restrict__ deg, int* __restrict__ partial, int N) {
    __shared__ int red[256];
    int base = blockIdx.x * 1024;
    int s = 0;
    for (int i = threadIdx.x; i < 1024; i += 256) {
        int idx = base + i;
        s += (idx < N) ? ((deg[idx] + 3) & ~3) : 0;   // padded slots
    }
    red[threadIdx.x] = s;
    __syncthreads();
    for (int off = 128; off > 0; off >>= 1) {
        if (threadIdx.x < off) red[threadIdx.x] += red[threadIdx.x + off];
        __syncthreads();
    }
    if (threadIdx.x == 0) partial[blockIdx.x] = red[0];
}

__global__ void scan_partials(int* __restrict__ partial, int nb,
                              int* __restrict__ row_start, int N) {
    if (threadIdx.x == 0 && blockIdx.x == 0) {
        int acc = 0;
        for (int i = 0; i < nb; i++) { int v = partial[i]; partial[i] = acc; acc += v; }
        row_start[N] = acc;   // total padded slots
    }
}

__global__ void scan_chunks(const int* __restrict__ deg, const int* __restrict__ partial,
                            int* __restrict__ row_start, float* __restrict__ dinv,
                            float* __restrict__ u0, int N) {
    __shared__ int buf[2][1024];
    int t = threadIdx.x;
    int gid = blockIdx.x * 1024 + t;
    int d = (gid < N) ? deg[gid] : 0;
    int v = (gid < N) ? ((d + 3) & ~3) : 0;           // padded slots
    int cur = 0;
    buf[0][t] = v;
    __syncthreads();
    for (int off = 1; off < 1024; off <<= 1) {
        int nxt = cur ^ 1;
        int val = buf[cur][t];
        if (t >= off) val += buf[cur][t - off];
        buf[nxt][t] = val;
        cur = nxt;
        __syncthreads();
    }
    int incl = buf[cur][t];
    if (gid < N) {
        row_start[gid] = partial[blockIdx.x] + incl - v;  // exclusive
        float dv = rsqrtf((float)(d + 1));                // +1 self loop
        dinv[gid] = dv;
        u0[gid] = dv;                                     // u0 = dinv .* ones
    }
}

__global__ void fill_csr(const int* __restrict__ ei, int E,
                         const int* __restrict__ row_start,
                         int* __restrict__ cursor, int* __restrict__ csr_src) {
    int e = blockIdx.x * blockDim.x + threadIdx.x;
    if (e < E) {
        int s = ei[e];
        int d = ei[E + e];
        int pos = atomicAdd(&cursor[d], 1);
        csr_src[row_start[d] + pos] = s;
    }
}

// ---------------- GEMM: C = act(rowscale * (A @ BT^T) + bias) ----------------
// R0-proven structure (best of 4 schedule experiments R1-R4): 128x128 tile,
// 4 waves, BK=64 single buffer, global_load_lds w=16, 4 blocks/CU.
// R6 post-mortem: the "generic" epilogue copy was WRONG for N=512 (copied
// rowbytes per row instead of the fixed 256B tile width, cross-block
// clobber). Restored the proven copy loop — it is already N-generic
// (tile width is always 128 cols = 256 data bytes; only the output row
// stride rowbytes varies).

template <bool F32OUT, bool RELU>
__global__ __launch_bounds__(256, 4) void gemm_tile(
    const bf16_t* __restrict__ A, const bf16_t* __restrict__ BT,
    const float* __restrict__ bias, const float* __restrict__ rowscale,
    void* __restrict__ Cv, int M, int N, int K)
{
    __shared__ __align__(16) char smem[32768];  // sA 16KB + sB 16KB; epilogue reuse
    bf16_t* sA = (bf16_t*)smem;
    bf16_t* sB = (bf16_t*)(smem + 128 * 128);
    bf16_t* sC = (bf16_t*)smem;                 // 64 x 136 bf16 = 17.4 KB

    int bxi, byi;
    if (gridDim.x == 4) {
        const int bid = blockIdx.y * 4 + blockIdx.x;     // dispatch-linear id
        const int T0 = (int)(gridDim.y * 4) & ~31;
        if (bid < T0) { int q = bid >> 5, r = bid & 31; byi = q * 8 + (r & 7); bxi = r >> 3; }
        else          { int t = bid - T0; byi = (T0 >> 2) + (t >> 2); bxi = t & 3; }
    } else { bxi = blockIdx.x; byi = blockIdx.y; }

    const int tid  = threadIdx.x;
    const int lane = tid & 63;
    const int wave = tid >> 6;
    const int bn = bxi * 128;
    const int bm = byi * 128;
    const int wm = (wave & 1) * 64;
    const int wn = (wave >> 1) * 64;
    const int lm = lane & 15;
    const int lq = lane >> 4;

    // staging: each 1KB wave-load covers 8 rows x 8 chunks; lane (r8,c8)
    const int r8 = lane >> 3;
    const int c8 = lane & 7;
    const int ksw = (c8 ^ r8) * 8;              // swizzled k-offset (elements)

    f32x4 acc[4][4] = {};

    const int nkb = K >> 6;
    for (int kb = 0; kb < nkb; kb++) {
        const int k0 = kb * 64;
#pragma unroll
        for (int r = 0; r < 4; r++) {               // A: 16 groups of 8 rows
            const int g = r * 4 + wave;
            __builtin_amdgcn_global_load_lds(
                (const AS1 unsigned int*)(A + (size_t)(bm + g * 8 + r8) * K + k0 + ksw),
                (AS3 unsigned int*)((AS3 char*)(AS3 bf16_t*)sA + g * 1024),
                16, 0, 0);
        }
#pragma unroll
        for (int r = 0; r < 4; r++) {               // B: 16 groups of 8 rows
            const int g = r * 4 + wave;
            __builtin_amdgcn_global_load_lds(
                (const AS1 unsigned int*)(BT + (size_t)(bn + g * 8 + r8) * K + k0 + ksw),
                (AS3 unsigned int*)((AS3 char*)(AS3 bf16_t*)sB + g * 1024),
                16, 0, 0);
        }
        __syncthreads();

#pragma unroll
        for (int s = 0; s < 2; s++) {               // two K=32 steps per BK=64
            bf16x8 af[4], bfr[4];
#pragma unroll
            for (int mt = 0; mt < 4; mt++) {
                const int R = wm + mt * 16 + lm;
                const int g = s * 4 + lq;
                af[mt] = *reinterpret_cast<bf16x8*>(&sA[R * 64 + ((g ^ (R & 7)) * 8)]);
            }
#pragma unroll
            for (int nt = 0; nt < 4; nt++) {
                const int R = wn + nt * 16 + lm;
                const int g = s * 4 + lq;
                bfr[nt] = *reinterpret_cast<bf16x8*>(&sB[R * 64 + ((g ^ (R & 7)) * 8)]);
            }
#pragma unroll
            for (int mt = 0; mt < 4; mt++)
#pragma unroll
                for (int nt = 0; nt < 4; nt++)
                    acc[mt][nt] = __builtin_amdgcn_mfma_f32_16x16x32_bf16(af[mt], bfr[nt], acc[mt][nt], 0, 0, 0);
        }
        __syncthreads();
    }

    if (!F32OUT) {
        // coalesced epilogue: 2 passes of 64 rows through LDS; sC row stride 136 elems
        const size_t rowbytes = (size_t)N * 2;
#pragma unroll
        for (int p = 0; p < 2; p++) {
            if (p) __syncthreads();
            if ((wave & 1) == p) {
#pragma unroll
                for (int nt = 0; nt < 4; nt++) {
                    const int col = wn + nt * 16 + lm;
                    const float bv = bias ? bias[bn + col] : 0.0f;
#pragma unroll
                    for (int mt = 0; mt < 4; mt++) {
#pragma unroll
                        for (int r = 0; r < 4; r++) {
                            const int lrow = mt * 16 + lq * 4 + r;
                            float v = acc[mt][nt][r] + bv;
                            if (rowscale) v *= rowscale[bm + p * 64 + lrow];
                            if (RELU) v = fmaxf(v, 0.0f);
                            sC[lrow * 136 + col] = (bf16_t)v;
                        }
                    }
                }
            }
            __syncthreads();
            char* outbase = (char*)Cv + (size_t)(bm + p * 64) * rowbytes + (size_t)bn * 2;
#pragma unroll
            for (int j = 0; j < 4; j++) {
                const int idx = j * 4096 + tid * 16;
                const int row = idx >> 8;            // 256 data bytes per tile row
                const int colb = idx & 255;
                *reinterpret_cast<uint4*>(outbase + (size_t)row * rowbytes + colb) =
                    *reinterpret_cast<const uint4*>((char*)sC + (size_t)row * 272 + colb);
            }
        }
    } else {
        // scattered epilogue (fp32 out): C/D layout col=lane&15, row=lq*4+reg
#pragma unroll
        for (int nt = 0; nt < 4; nt++) {
            const int col = bn + wn + nt * 16 + lm;
            const float bv = bias ? bias[col] : 0.0f;
#pragma unroll
            for (int mt = 0; mt < 4; mt++) {
#pragma unroll
                for (int r = 0; r < 4; r++) {
                    const int row = bm + wm + mt * 16 + lq * 4 + r;
                    if (row < M) {
                        float v = acc[mt][nt][r] + bv;
                        if (rowscale) v *= rowscale[row];
                        if (RELU) v = fmaxf(v, 0.0f);
                        ((float*)Cv)[(size_t)row * N + col] = v;
                    }
                }
            }
        }
    }
}

// ---------------- mm3: small fp32-accurate GEMM via on-the-fly split-bf16 ----------------
// C[m][n] (+)= sum_k A[m][k]*BT[n][k], computed as Ah*Bh + Al*Bh + Ah*Bl (err ~2^-16).
// A, BT fp32 row-major with row length K. Block = 64x64 tile (4 waves, wave w = rows w*16..).
// Grid (N/64, M/64, Z): z = K-chunk (kc chunks, atomicAdd when kc>1); for a combined
// launch of two independent products, Z = 2*kc and z>=kc selects the second triple.
// outmode 0: atomicAdd fp32 into C (pre-zeroed). outmode 1 (kc==1): direct bf16 store to Cb.

__global__ __launch_bounds__(256) void mm3(
    const float* __restrict__ A0, const float* __restrict__ B0, float* __restrict__ C0,
    const float* __restrict__ A1, const float* __restrict__ B1, float* __restrict__ C1,
    bf16_t* __restrict__ Cb, int M, int N, int K, int kc, int outmode)
{
    int z = blockIdx.z;
    const float* A = A0; const float* BT = B0; float* C = C0;
    if (z >= kc) { A = A1; BT = B1; C = C1; z -= kc; }
    const int n0 = blockIdx.x * 64;
    const int m0 = blockIdx.y * 64;
    const int lane = threadIdx.x & 63;
    const int w    = threadIdx.x >> 6;
    const int lm = lane & 15, lq = lane >> 4;
    const int klen = K / kc;
    const int kbeg = z * klen;
    const int arow = m0 + w * 16 + lm;

    f32x4 acc[4] = {};
    for (int k = kbeg; k < kbeg + klen; k += 32) {
        const float* ap = A + (size_t)arow * K + k + lq * 8;
        float4 av0 = *reinterpret_cast<const float4*>(ap);
        float4 av1 = *reinterpret_cast<const float4*>(ap + 4);
        float av[8] = {av0.x, av0.y, av0.z, av0.w, av1.x, av1.y, av1.z, av1.w};
        bf16x8 ah, al;
#pragma unroll
        for (int j = 0; j < 8; j++) {
            bf16_t h = (bf16_t)av[j]; ah[j] = h; al[j] = (bf16_t)(av[j] - (float)h);
        }
#pragma unroll
        for (int nt = 0; nt < 4; nt++) {
            const float* bp = BT + (size_t)(n0 + nt * 16 + lm) * K + k + lq * 8;
            float4 bv0 = *reinterpret_cast<const float4*>(bp);
            float4 bv1 = *reinterpret_cast<const float4*>(bp + 4);
            float bv[8] = {bv0.x, bv0.y, bv0.z, bv0.w, bv1.x, bv1.y, bv1.z, bv1.w};
            bf16x8 bh, bl;
#pragma unroll
            for (int j = 0; j < 8; j++) {
                bf16_t h = (bf16_t)bv[j]; bh[j] = h; bl[j] = (bf16_t)(bv[j] - (float)h);
            }
            acc[nt] = __builtin_amdgcn_mfma_f32_16x16x32_bf16(ah, bh, acc[nt], 0, 0, 0);
            acc[nt] = __builtin_amdgcn_mfma_f32_16x16x32_bf16(al, bh, acc[nt], 0, 0, 0);
            acc[nt] = __builtin_amdgcn_mfma_f32_16x16x32_bf16(ah, bl, acc[nt], 0, 0, 0);
        }
    }
#pragma unroll
    for (int nt = 0; nt < 4; nt++) {
#pragma unroll
        for (int r = 0; r < 4; r++) {
            const int row = m0 + w * 16 + lq * 4 + r;
            const int col = n0 + nt * 16 + lm;
            if (outmode == 0) atomicAdd(&C[(size_t)row * N + col], acc[nt][r]);
            else              Cb[(size_t)row * N + col] = (bf16_t)acc[nt][r];
        }
    }
}

// ---------------- vstep: bias-chain propagation (rows of V through one weight) ----------
// Vout[r][c] = (r < rcnt) ? sum_k Vin[r][k]*W[k][c] (+ addb[c] if r==3) : Vin[r][c]
// Vin rows stride 512. Grid = Ncols/64, block 256 (4 rows x 64 cols).

__global__ void vstep(const float* __restrict__ Vin, const float* __restrict__ W,
                      float* __restrict__ Vout, int rcnt, int Ncols,
                      const float* __restrict__ addb) {
    const int r = threadIdx.x >> 6;
    const int c = blockIdx.x * 64 + (threadIdx.x & 63);
    if (r < rcnt) {
        float acc = 0.0f;
        for (int k = 0; k < D_HID; k++) acc += Vin[r * D_HID + k] * W[(size_t)k * Ncols + c];
        if (addb && r == 3) acc += addb[c];
        Vout[r * Ncols + c] = acc;
    } else {
        Vout[r * Ncols + c] = Vin[r * D_HID + c];
    }
}

// ---------------- s_agg: scalar aggregate s = dinv .* (u[self] + gather-sum) -------------
// uin prescaled (u = dinv .* s_prev); uin[ZROW] = 0 absorbs dummy slots.

__global__ void s_agg(const float* __restrict__ uin, const float* __restrict__ dinv,
                      const int* __restrict__ row_start, const int* __restrict__ csr_src,
                      float* __restrict__ sout, float* __restrict__ uout, int N)
{
    int n = blockIdx.x * blockDim.x + threadIdx.x;
    if (n >= N) return;
    float a = uin[n];
    const int beg = row_start[n], end = row_start[n + 1];
    for (int i = beg; i < end; i++) a += uin[csr_src[i]];
    const float sv = dinv[n] * a;
    sout[n] = sv;
    uout[n] = dinv[n] * sv;
}

// ---------------- agg128: one hop of Ahat on a 128-wide table ----------------
// tin prescaled (t = dinv .* G_prev), rows 256B; ZROW zero. One wave per node,
// lane = feature pair (1 dword). 8 slots/iter: 2 int4 idx loads + 8 dword gathers.
// !FINAL: tout[n] = dinv[n]^2 * raw (prescaled for next hop), bf16.
// FINAL:  fout[n] = dinv[n]*raw + s3*c1 + s2*c2 + s1*c3 + c4  (fp32, the model output).

template <bool FINAL>
__global__ __launch_bounds__(256) void agg128(
    const bf16_t* __restrict__ tin, const float* __restrict__ dinv,
    const int* __restrict__ row_start, const int* __restrict__ csr_src,
    bf16_t* __restrict__ tout, float* __restrict__ fout,
    const float* __restrict__ s1, const float* __restrict__ s2,
    const float* __restrict__ s3, const float* __restrict__ cvec, int N)
{
    const int n = blockIdx.x * 4 + (threadIdx.x >> 6);
    const int lane = threadIdx.x & 63;
    if (n >= N) return;
    const float dn = dinv[n];
    const char* tb = (const char*)tin + lane * 4;

    f32x2 acc;
    {
        unsigned u = *reinterpret_cast<const unsigned*>(tb + ((size_t)n << 8));
        acc[0] = __uint_as_float(u << 16);
        acc[1] = __uint_as_float(u & 0xffff0000u);
    }
    const int beg = row_start[n];
    const int cnt = row_start[n + 1] - beg;      // multiple of 4
    const int* ip = csr_src + beg;

    int i = 0;
    for (; i + 8 <= cnt; i += 8) {
        const int4 a = *reinterpret_cast<const int4*>(ip + i);
        const int4 b = *reinterpret_cast<const int4*>(ip + i + 4);
        unsigned u[8];
        u[0] = *reinterpret_cast<const unsigned*>(tb + ((size_t)a.x << 8));
        u[1] = *reinterpret_cast<const unsigned*>(tb + ((size_t)a.y << 8));
        u[2] = *reinterpret_cast<const unsigned*>(tb + ((size_t)a.z << 8));
        u[3] = *reinterpret_cast<const unsigned*>(tb + ((size_t)a.w << 8));
        u[4] = *reinterpret_cast<const unsigned*>(tb + ((size_t)b.x << 8));
        u[5] = *reinterpret_cast<const unsigned*>(tb + ((size_t)b.y << 8));
        u[6] = *reinterpret_cast<const unsigned*>(tb + ((size_t)b.z << 8));
        u[7] = *reinterpret_cast<const unsigned*>(tb + ((size_t)b.w << 8));
#pragma unroll
        for (int q = 0; q < 8; q++) {
            acc[0] += __uint_as_float(u[q] << 16);
            acc[1] += __uint_as_float(u[q] & 0xffff0000u);
        }
    }
    if (i < cnt) {                               // one final 4-slot chunk
        const int4 a = *reinterpret_cast<const int4*>(ip + i);
        unsigned u[4];
        u[0] = *reinterpret_cast<const unsigned*>(tb + ((size_t)a.x << 8));
        u[1] = *reinterpret_cast<const unsigned*>(tb + ((size_t)a.y << 8));
        u[2] = *reinterpret_cast<const unsigned*>(tb + ((size_t)a.z << 8));
        u[3] = *reinterpret_cast<const unsigned*>(tb + ((size_t)a.w << 8));
#pragma unroll
        for (int q = 0; q < 4; q++) {
            acc[0] += __uint_as_float(u[q] << 16);
            acc[1] += __uint_as_float(u[q] & 0xffff0000u);
        }
    }

    if (!FINAL) {
        const float sc = dn * dn;
        bf16_t o2[2] = {(bf16_t)(sc * acc[0]), (bf16_t)(sc * acc[1])};
        *reinterpret_cast<unsigned*>((char*)tout + ((size_t)n << 8) + lane * 4) =
            *reinterpret_cast<const unsigned*>(o2);
    } else {
        const int f = lane * 2;
        const float w3 = s3[n], w2 = s2[n], w1 = s1[n];
        float o0 = dn * acc[0] + w3 * cvec[f]     + w2 * cvec[128 + f]
                 + w1 * cvec[256 + f]     + cvec[384 + f];
        float o1 = dn * acc[1] + w3 * cvec[f + 1] + w2 * cvec[128 + f + 1]
                 + w1 * cvec[256 + f + 1] + cvec[384 + f + 1];
        float2 ov = make_float2(o0, o1);
        *reinterpret_cast<float2*>(fout + (size_t)n * D_OUT + f) = ov;
    }
}

// ---------------- orchestration ----------------
// Algebra (GCN layers are LINEAR — no activation between them):
//   out = Ahat^4 (h0 @ Wbig) + s3 (x) c1 + s2 (x) c2 + s1 (x) c3 + 1 (x) c4
//   Wbig = C1 C2 C3 C4 W2 (512x128), s_k = Ahat^k 1, c_k = bias chains.
// Heavy runtime ops shrink to: dnn1 GEMM, one Nx128 GEMM, four 128-wide aggregates.

extern "C" void kernel_launch(void* const* d_in, const int* in_sizes, int n_in,
                              void* d_out, int out_size, void* d_ws, size_t ws_size,
                              hipStream_t stream) {
    const int N = N_NODES, E = N_EDGES;
    const size_t DD = (size_t)D_HID * D_HID;

    const float* x  = (const float*)d_in[0];
    const int*   ei = (const int*)d_in[1];
    const float* W1 = (const float*)d_in[2];
    const float* b1 = (const float*)d_in[3];
    const float* Wc = (const float*)d_in[4];
    const float* bc = (const float*)d_in[5];
    const float* W2 = (const float*)d_in[6];
    const float* b2 = (const float*)d_in[7];
    float* out = (float*)d_out;

    char* ws = (char*)d_ws;
    size_t off = 0;
    auto alloc = [&](size_t bytes) -> void* {
        void* p = ws + off;
        off += (bytes + 255) & ~(size_t)255;
        return p;
    };
    int*    deg       = (int*)alloc((size_t)N * 4);
    int*    cursor    = (int*)alloc((size_t)N * 4);
    int*    row_start = (int*)alloc((size_t)(N + 1) * 4);
    int*    partial   = (int*)alloc(256 * 4);
    float*  dinv      = (float*)alloc((size_t)N_PAD * 4);
    float*  u0        = (float*)alloc((size_t)(N_PAD + 1) * 4);
    float*  u1        = (float*)alloc((size_t)(N_PAD + 1) * 4);
    float*  u2        = (float*)alloc((size_t)(N_PAD + 1) * 4);
    float*  s1        = (float*)alloc((size_t)N * 4);
    float*  s2        = (float*)alloc((size_t)N * 4);
    float*  s3        = (float*)alloc((size_t)N * 4);
    int*    csr_src   = (int*)alloc((size_t)CSR_CAP * 4);
    bf16_t* xb        = (bf16_t*)alloc((size_t)N_PAD * D_IN * 2);
    bf16_t* h0        = (bf16_t*)alloc((size_t)N_PAD * D_HID * 2);
    bf16_t* FA        = (bf16_t*)alloc((size_t)(N_PAD + 1) * D_OUT * 2);  // +1: ZROW
    bf16_t* FB        = (bf16_t*)alloc((size_t)(N_PAD + 1) * D_OUT * 2);  // +1: ZROW
    bf16_t* W1t       = (bf16_t*)alloc((size_t)D_HID * D_IN * 2);
    float*  W2cT      = (float*)alloc(DD * 4);
    float*  W4cT      = (float*)alloc(DD * 4);
    float*  W2T       = (float*)alloc((size_t)D_OUT * D_HID * 4);
    float*  Pz        = (float*)alloc(3 * DD * 4);     // P12 | Q | P (zeroed together)
    float*  P12 = Pz, *Q = Pz + DD, *P = Pz + 2 * DD;
    bf16_t* WbigT     = (bf16_t*)alloc((size_t)D_OUT * D_HID * 2);
    float*  V0        = (float*)alloc(4 * 512 * 4);
    float*  V1        = (float*)alloc(4 * 512 * 4);
    float*  cvec      = (float*)alloc(4 * 128 * 4);

    // init (zero deg/cursor, dummy csr fill, pads, ZROW rows, P buffers)
    init_misc<<<(PZ_FLOATS + 255) / 256, 256, 0, stream>>>(
        deg, cursor, csr_src, dinv, u0, u1, u2, FA, FB, Pz);

    // conversions
    {
        int n = N * D_IN;
        f32_to_bf16<<<(n / 4 + 255) / 256, 256, 0, stream>>>(x, xb, n);
        transpose_all<<<dim3(16, 16, 4), dim3(32, 8), 0, stream>>>(
            W1, Wc, W2, W1t, W2cT, W4cT, W2T);
    }

    // padded CSR build
    count_deg<<<(E + 255) / 256, 256, 0, stream>>>(ei + E, deg, E);
    const int nch = (N + 1023) / 1024;
    scan_reduce<<<nch, 256, 0, stream>>>(deg, partial, N);
    scan_partials<<<1, 64, 0, stream>>>(partial, nch, row_start, N);
    scan_chunks<<<nch, 1024, 0, stream>>>(deg, partial, row_start, dinv, u0, N);
    fill_csr<<<(E + 255) / 256, 256, 0, stream>>>(ei, E, row_start, cursor, csr_src);

    // weight chain (fp32-accurate): P12 = C1@C2, Q = (C3@C4)^T, P = P12@(C3C4),
    // WbigT = (P@W2)^T as bf16 [128][512]
    mm3<<<dim3(8, 8, 8), 256, 0, stream>>>(
        Wc, W2cT, P12,                 // product A: C1 @ C2
        W4cT, Wc + 2 * DD, Q,          // product B: C4^T @ C3^T = (C3 C4)^T
        nullptr, 512, 512, 512, 4, 0);
    mm3<<<dim3(8, 8, 4), 256, 0, stream>>>(
        P12, Q, P, P12, Q, P, nullptr, 512, 512, 512, 4, 0);
    mm3<<<dim3(8, 2, 1), 256, 0, stream>>>(
        W2T, P, P, W2T, P, P, WbigT, 128, 512, 512, 1, 1);

    // bias chains: cvec rows = [b1*C2C3C4W2, b2*C3C4W2, b3*C4W2, b4*W2 + b2out]
    vstep<<<8, 256, 0, stream>>>(bc, Wc + DD,     V0,   1, 512, nullptr);
    vstep<<<8, 256, 0, stream>>>(V0, Wc + 2 * DD, V1,   2, 512, nullptr);
    vstep<<<8, 256, 0, stream>>>(V1, Wc + 3 * DD, V0,   3, 512, nullptr);
    vstep<<<2, 256, 0, stream>>>(V0, W2,          cvec, 4, 128, b2);

    // s_k = Ahat^k 1
    s_agg<<<(N + 255) / 256, 256, 0, stream>>>(u0, dinv, row_start, csr_src, s1, u1, N);
    s_agg<<<(N + 255) / 256, 256, 0, stream>>>(u1, dinv, row_start, csr_src, s2, u2, N);
    s_agg<<<(N + 255) / 256, 256, 0, stream>>>(u2, dinv, row_start, csr_src, s3, u1, N);

    const dim3 blk(256);
    const int mg = N_PAD / 128;  // 391

    // dnn1: h0 = relu(x @ W1 + b1)
    gemm_tile<false, true><<<dim3(4, mg), blk, 0, stream>>>(
        xb, W1t, b1, nullptr, h0, N_PAD, D_HID, D_IN);

    // F = dinv .* (h0 @ Wbig)  (prescaled table t0, bf16 128-wide)
    gemm_tile<false, false><<<dim3(1, mg), blk, 0, stream>>>(
        h0, WbigT, nullptr, dinv, FA, N_PAD, D_OUT, D_HID);

    // four hops of Ahat (128-wide); last fuses the rank-4 bias correction + fp32 out
    const int ag = (N + 3) / 4;
    agg128<false><<<ag, blk, 0, stream>>>(FA, dinv, row_start, csr_src, FB, nullptr,
                                          nullptr, nullptr, nullptr, nullptr, N);
    agg128<false><<<ag, blk, 0, stream>>>(FB, dinv, row_start, csr_src, FA, nullptr,
                                          nullptr, nullptr, nullptr, nullptr, N);
    agg128<false><<<ag, blk, 0, stream>>>(FA, dinv, row_start, csr_src, FB, nullptr,
                                          nullptr, nullptr, nullptr, nullptr, N);
    agg128<true><<<ag, blk, 0, stream>>>(FB, dinv, row_start, csr_src, nullptr, out,
                                         s1, s2, s3, cvec, N);
}